// Round 5
// baseline (396.915 us; speedup 1.0000x reference)
//
#include <hip/hip_runtime.h>
#include <math.h>

#define NPOS 2304   // 48*48
#define CC   256    // DIM
#define DI   512    // HEADS*DIM_HEAD
#define NT   36     // NPOS/64
#define SCALE 0.125f
#define MASKV -100.0f
// exp(-SCALE*sqrt(d2)) = exp2(-SCALE*log2(e)*sqrt(d2))
#define NEGSL2E (-0.18033688011112042f)

typedef __attribute__((ext_vector_type(8))) short bf16x8;  // 8 bf16 (4 VGPRs)
typedef __attribute__((ext_vector_type(4))) float f32x4;   // MFMA C/D frag
typedef unsigned short u16;
typedef unsigned int u32;

__device__ inline u16 f2bf(float f) {
    union { float f; unsigned int u; } v; v.f = f;
    return (u16)((v.u + 0x7fffu + ((v.u >> 16) & 1u)) >> 16);
}

// ---------------- Kernel 1: ChannelRMSNorm ----------------
__global__ __launch_bounds__(256) void k_rmsnorm(const float* __restrict__ fmap,
                                                 const float* __restrict__ gamma,
                                                 float* __restrict__ normed) {
    const int b  = blockIdx.y;
    const int j0 = blockIdx.x * 64;
    const int tx = threadIdx.x & 63;
    const int ty = threadIdx.x >> 6;
    __shared__ float red[4][64];
    __shared__ float inv[64];
    __shared__ float gs[256];
    gs[threadIdx.x] = gamma[threadIdx.x];
    const float* fb = fmap + (size_t)b * CC * NPOS;
    float s = 0.0f;
#pragma unroll 8
    for (int i = 0; i < 64; ++i) {
        const int c = ty + 4 * i;
        const float v = fb[c * NPOS + j0 + tx];
        s += v * v;
    }
    red[ty][tx] = s;
    __syncthreads();
    if (threadIdx.x < 64) {
        const float t = red[0][tx] + red[1][tx] + red[2][tx] + red[3][tx];
        inv[tx] = 16.0f / fmaxf(sqrtf(t), 1e-12f);
    }
    __syncthreads();
    float* nb = normed + (size_t)b * CC * NPOS;
#pragma unroll 8
    for (int i = 0; i < 64; ++i) {
        const int c = ty + 4 * i;
        nb[c * NPOS + j0 + tx] = fb[c * NPOS + j0 + tx] * inv[tx] * gs[c];
    }
}

// ---------------- Kernel 2: fused qk/v projection GEMM ----------------
// fp32 accumulate; emits bf16 qkh[b,h,n,64] + fp32 sq/ndot, and V in
// MFMA-fragment order: vt[bh][kb32][dim64][32] (kb = key/32, inner = quad*8+j).
__global__ __launch_bounds__(256) void k_proj(const float* __restrict__ normed,
                                              const float* __restrict__ w_qk,
                                              const float* __restrict__ w_v,
                                              const float* __restrict__ null_kv,
                                              u16* __restrict__ qkh,
                                              u16* __restrict__ vt,
                                              float* __restrict__ sq,
                                              float* __restrict__ ndot) {
    const int b  = blockIdx.z;
    const int o0 = blockIdx.y * 64;   // 0..1023
    const int j0 = blockIdx.x * 64;
    const int t  = threadIdx.x;
    const int trow = t >> 4, tcol = t & 15;
    __shared__ float Ast[16][68];   // Ast[k][o]
    __shared__ float Bs[16][68];    // Bs[k][j]
    __shared__ u16 Tt[64][72];      // bf16 transpose staging [j][d]
    __shared__ float nks[64];
    float acc[4][4] = {};
    const float* W = (o0 < DI) ? w_qk : w_v;
    const int or0 = (o0 < DI) ? o0 : (o0 - DI);
    const int h = or0 >> 6;
    if (o0 < DI && t < 64) nks[t] = null_kv[h * 64 + t];
    const float* nbp = normed + (size_t)b * CC * NPOS;
    for (int k0 = 0; k0 < 256; k0 += 16) {
        {
            const int o = t >> 2, kq = t & 3;
            const float4 w4 = *(const float4*)&W[(or0 + o) * 256 + k0 + kq * 4];
            Ast[kq * 4 + 0][o] = w4.x; Ast[kq * 4 + 1][o] = w4.y;
            Ast[kq * 4 + 2][o] = w4.z; Ast[kq * 4 + 3][o] = w4.w;
        }
        {
            const int kk = t >> 4, jq = t & 15;
            const float4 b4 = *(const float4*)&nbp[(k0 + kk) * NPOS + j0 + jq * 4];
            *(float4*)&Bs[kk][jq * 4] = b4;
        }
        __syncthreads();
#pragma unroll
        for (int kk = 0; kk < 16; ++kk) {
            const float4 a4 = *(const float4*)&Ast[kk][trow * 4];
            const float4 b4 = *(const float4*)&Bs[kk][tcol * 4];
            const float a[4]  = {a4.x, a4.y, a4.z, a4.w};
            const float bb[4] = {b4.x, b4.y, b4.z, b4.w};
#pragma unroll
            for (int i = 0; i < 4; ++i)
#pragma unroll
                for (int j = 0; j < 4; ++j)
                    acc[i][j] += a[i] * bb[j];
        }
        __syncthreads();
    }
    if (o0 < DI) {
        float sjj[4], njj[4];
#pragma unroll
        for (int jj = 0; jj < 4; ++jj) {
            float ts = 0.0f, tn = 0.0f;
#pragma unroll
            for (int i = 0; i < 4; ++i) {
                ts += acc[i][jj] * acc[i][jj];
                tn += acc[i][jj] * nks[trow * 4 + i];
            }
            sjj[jj] = ts; njj[jj] = tn;
        }
        *(float4*)&Ast[trow][tcol * 4] = make_float4(sjj[0], sjj[1], sjj[2], sjj[3]);
        *(float4*)&Bs[trow][tcol * 4]  = make_float4(njj[0], njj[1], njj[2], njj[3]);
#pragma unroll
        for (int i = 0; i < 4; ++i)
#pragma unroll
            for (int jj = 0; jj < 4; ++jj)
                Tt[tcol * 4 + jj][trow * 4 + i] = f2bf(acc[i][jj]);
        __syncthreads();
        if (t < 64) {
            float s = 0.0f, n = 0.0f;
#pragma unroll
            for (int r = 0; r < 16; ++r) { s += Ast[r][t]; n += Bs[r][t]; }
            sq  [((size_t)b * 8 + h) * NPOS + j0 + t] = s;
            ndot[((size_t)b * 8 + h) * NPOS + j0 + t] = n;
        }
        const int row = t >> 2, seg = t & 3;
        const int4 w0 = *(const int4*)&Tt[row][seg * 16];
        const int4 w1 = *(const int4*)&Tt[row][seg * 16 + 8];
        u16* dst = qkh + (((size_t)b * 8 + h) * NPOS + j0 + row) * 64 + seg * 16;
        *(int4*)&dst[0] = w0;
        *(int4*)&dst[8] = w1;
    } else {
        // V: fragment-ordered store vt[bh][kb][d][quad*8 + j]
        const size_t vb_base = (size_t)(b * 8 + h) * (72 * 64 * 32);
        const int kb   = (j0 >> 5) + (tcol >> 3);
        const int quad = (tcol >> 1) & 3;
        const int joff = (tcol & 1) * 4;
#pragma unroll
        for (int i = 0; i < 4; ++i) {
            const int d = trow * 4 + i;
            ushort4 r4;
            r4.x = f2bf(acc[i][0]); r4.y = f2bf(acc[i][1]);
            r4.z = f2bf(acc[i][2]); r4.w = f2bf(acc[i][3]);
            *(ushort4*)&vt[vb_base + ((size_t)kb * 64 + d) * 32 + quad * 8 + joff] = r4;
        }
    }
}

// ---------------- Kernel 3: K-split MFMA flash attention ----------------
// 4 waves/block, all on the same 16 queries; wave w covers K-tiles [9w, 9w+9).
// m=0 fixed softmax (sim <= 0) makes O and l linear in keys -> exact partial
// merge via one LDS reduction. P slice stays wave-private (no barrier in loop).
__global__ __launch_bounds__(256) void k_attn(const u16* __restrict__ qkh,
                                              const u16* __restrict__ vt,
                                              const float* __restrict__ null_kv,
                                              const float* __restrict__ sq,
                                              const float* __restrict__ ndot,
                                              float* __restrict__ inner) {
    const int q16 = blockIdx.x * 16;            // 144 query tiles of 16
    const int bh = blockIdx.y;
    const int b = bh >> 3, h = bh & 7;
    const int t = threadIdx.x;
    const int wave = t >> 6, lane = t & 63;
    const int mcol = lane & 15, quad = lane >> 4;

    // union: per-wave Pt[16][72] u16 (4x2304B) || reduction buf float[256][18]
    __shared__ __align__(16) char smem[18432];
    u16 (*Pt)[72] = (u16(*)[72])(smem + wave * 2304);

    const u16* qbase = qkh + (size_t)bh * NPOS * 64;
    const u16* vbase = vt + (size_t)bh * (72 * 64 * 32);
    const float* sqb = sq + (size_t)bh * NPOS;

    // Q B-frags: n = query = mcol, contraction = d (two K=32 chunks)
    const bf16x8 bq0 = *(const bf16x8*)&qbase[(q16 + mcol) * 64 + quad * 8];
    const bf16x8 bq1 = *(const bf16x8*)&qbase[(q16 + mcol) * 64 + 32 + quad * 8];
    const float q2 = sqb[q16 + mcol];

    const bf16x8 ones = {0x3F80, 0x3F80, 0x3F80, 0x3F80, 0x3F80, 0x3F80, 0x3F80, 0x3F80};
    const int ktm = q16 >> 6, nbm = (q16 >> 4) & 3;

    f32x4 oacc[4];
#pragma unroll
    for (int nb = 0; nb < 4; ++nb) oacc[nb] = (f32x4){0.f, 0.f, 0.f, 0.f};
    f32x4 lsum = (f32x4){0.f, 0.f, 0.f, 0.f};

    const int kt0 = wave * 9, kt1 = kt0 + 9;

    // K A-frag double buffer; prefetch first tile of this wave's range
    bf16x8 bk[2][4][2];
#pragma unroll
    for (int nb = 0; nb < 4; ++nb) {
        const u16* kr = &qbase[(kt0 * 64 + nb * 16 + mcol) * 64 + quad * 8];
        bk[0][nb][0] = *(const bf16x8*)&kr[0];
        bk[0][nb][1] = *(const bf16x8*)&kr[32];
    }

#pragma unroll 3
    for (int kt = kt0; kt < kt1; ++kt) {
        const int cur = kt & 1;
        const int kj0 = kt * 64;

        float4 k2q[4];
#pragma unroll
        for (int nb = 0; nb < 4; ++nb)
            k2q[nb] = *(const float4*)&sqb[kj0 + nb * 16 + quad * 4];

        // S^T = K.Q^T
        f32x4 c[4];
#pragma unroll
        for (int nb = 0; nb < 4; ++nb) {
            c[nb] = (f32x4){0.f, 0.f, 0.f, 0.f};
            c[nb] = __builtin_amdgcn_mfma_f32_16x16x32_bf16(bk[cur][nb][0], bq0, c[nb], 0, 0, 0);
            c[nb] = __builtin_amdgcn_mfma_f32_16x16x32_bf16(bk[cur][nb][1], bq1, c[nb], 0, 0, 0);
        }

        // prefetch next K tile
        const int kjn = (kt + 1 < kt1) ? kj0 + 64 : kt0 * 64;
#pragma unroll
        for (int nb = 0; nb < 4; ++nb) {
            const u16* kr = &qbase[(kjn + nb * 16 + mcol) * 64 + quad * 8];
            bk[cur ^ 1][nb][0] = *(const bf16x8*)&kr[0];
            bk[cur ^ 1][nb][1] = *(const bf16x8*)&kr[32];
        }
        // V A-frags, fragment-ordered layout (fully coalesced)
        bf16x8 bv[4][2];
#pragma unroll
        for (int nb = 0; nb < 4; ++nb) {
            bv[nb][0] = *(const bf16x8*)&vbase[((size_t)(kt * 2 + 0) * 64 + nb * 16 + mcol) * 32 + quad * 8];
            bv[nb][1] = *(const bf16x8*)&vbase[((size_t)(kt * 2 + 1) * 64 + nb * 16 + mcol) * 32 + quad * 8];
        }

        // softmax numerator: e = exp2(-c1*sqrt(max(q2+k2-2*qk, 0))), m = 0 fixed
#pragma unroll
        for (int nb = 0; nb < 4; ++nb) {
            float e[4];
#pragma unroll
            for (int r = 0; r < 4; ++r) {
                const float pre = q2 + ((const float*)&k2q[nb])[r];
                const float d2 = fmaxf(__builtin_fmaf(c[nb][r], -2.0f, pre), 0.0f);
                e[r] = __builtin_amdgcn_exp2f(NEGSL2E * __builtin_amdgcn_sqrtf(d2));
            }
            if (kt == ktm && nb == nbm) {
#pragma unroll
                for (int r = 0; r < 4; ++r)
                    if (quad * 4 + r == mcol) e[r] = 0.0f;   // exp(MASKV) ~ 0
            }
            const u32 p01 = __builtin_amdgcn_perm(__float_as_uint(e[1]), __float_as_uint(e[0]), 0x07060302u);
            const u32 p23 = __builtin_amdgcn_perm(__float_as_uint(e[3]), __float_as_uint(e[2]), 0x07060302u);
            *(uint2*)&Pt[mcol][nb * 16 + quad * 4] = make_uint2(p01, p23);
        }

        // P^T B-frags (wave-private LDS; in-wave DS ordering, no barrier)
        const bf16x8 bp0 = *(const bf16x8*)&Pt[mcol][quad * 8];
        const bf16x8 bp1 = *(const bf16x8*)&Pt[mcol][32 + quad * 8];

#pragma unroll
        for (int nb = 0; nb < 4; ++nb) {
            oacc[nb] = __builtin_amdgcn_mfma_f32_16x16x32_bf16(bv[nb][0], bp0, oacc[nb], 0, 0, 0);
            oacc[nb] = __builtin_amdgcn_mfma_f32_16x16x32_bf16(bv[nb][1], bp1, oacc[nb], 0, 0, 0);
        }
        lsum = __builtin_amdgcn_mfma_f32_16x16x32_bf16(ones, bp0, lsum, 0, 0, 0);
        lsum = __builtin_amdgcn_mfma_f32_16x16x32_bf16(ones, bp1, lsum, 0, 0, 0);
    }

    // ---- cross-wave reduction (O and l are key-linear: exact merge) ----
    __syncthreads();   // all waves done reading their Pt before aliasing as Ored
    float* my = (float*)smem + (size_t)t * 18;
#pragma unroll
    for (int nb = 0; nb < 4; ++nb)
#pragma unroll
        for (int r = 0; r < 4; ++r) my[nb * 4 + r] = oacc[nb][r];
    my[16] = lsum[0];
    __syncthreads();

    if (wave == 0) {
        float o[16], l = 0.0f;
#pragma unroll
        for (int i = 0; i < 16; ++i) o[i] = 0.0f;
#pragma unroll
        for (int w = 0; w < 4; ++w) {
            const float* src = (const float*)smem + (size_t)(w * 64 + lane) * 18;
#pragma unroll
            for (int i = 0; i < 16; ++i) o[i] += src[i];
            l += src[16];
        }
        // null key/value epilogue (m=0: beta = exp(sim_null))
        float nk2 = 0.0f;
#pragma unroll 8
        for (int d = 0; d < 64; ++d) { const float nk = null_kv[h * 64 + d]; nk2 += nk * nk; }
        const float nd = ndot[(size_t)bh * NPOS + q16 + mcol];
        const float d2n = fmaxf(q2 + nk2 - 2.0f * nd, 0.0f);
        const float beta = __expf(-sqrtf(d2n) * SCALE);
        const float il = 1.0f / (l + beta);

        float* ob = inner + ((size_t)b * NPOS + q16 + mcol) * DI + h * 64;
#pragma unroll
        for (int nb = 0; nb < 4; ++nb) {
            const float4 nv4 = *(const float4*)&null_kv[DI + h * 64 + nb * 16 + quad * 4];
            float4 r;
            r.x = (o[nb * 4 + 0] + beta * nv4.x) * il;
            r.y = (o[nb * 4 + 1] + beta * nv4.y) * il;
            r.z = (o[nb * 4 + 2] + beta * nv4.z) * il;
            r.w = (o[nb * 4 + 3] + beta * nv4.w) * il;
            *(float4*)&ob[nb * 16 + quad * 4] = r;
        }
    }
}

// ---------------- Kernel 4: output projection ----------------
__global__ __launch_bounds__(256) void k_out(const float* __restrict__ w_out,
                                             const float* __restrict__ inner,
                                             float* __restrict__ out) {
    const int b  = blockIdx.z;
    const int c0 = blockIdx.y * 64;
    const int j0 = blockIdx.x * 64;
    const int t  = threadIdx.x;
    const int trow = t >> 4, tcol = t & 15;
    __shared__ float Ast[16][68];  // Ast[k][c]
    __shared__ float Bst[16][68];  // Bst[k][j]
    float acc[4][4] = {};
    const float* ib = inner + (size_t)b * NPOS * DI;
    for (int k0 = 0; k0 < 512; k0 += 16) {
        {
            const int cr = t >> 2, kq = t & 3;
            const float4 w4 = *(const float4*)&w_out[(c0 + cr) * DI + k0 + kq * 4];
            Ast[kq * 4 + 0][cr] = w4.x; Ast[kq * 4 + 1][cr] = w4.y;
            Ast[kq * 4 + 2][cr] = w4.z; Ast[kq * 4 + 3][cr] = w4.w;
        }
        {
            const int jr = t >> 2, kq = t & 3;
            const float4 i4 = *(const float4*)&ib[(size_t)(j0 + jr) * DI + k0 + kq * 4];
            Bst[kq * 4 + 0][jr] = i4.x; Bst[kq * 4 + 1][jr] = i4.y;
            Bst[kq * 4 + 2][jr] = i4.z; Bst[kq * 4 + 3][jr] = i4.w;
        }
        __syncthreads();
#pragma unroll
        for (int kk = 0; kk < 16; ++kk) {
            const float4 a4 = *(const float4*)&Ast[kk][trow * 4];
            const float4 b4 = *(const float4*)&Bst[kk][tcol * 4];
            const float a[4]  = {a4.x, a4.y, a4.z, a4.w};
            const float bb[4] = {b4.x, b4.y, b4.z, b4.w};
#pragma unroll
            for (int i = 0; i < 4; ++i)
#pragma unroll
                for (int j = 0; j < 4; ++j)
                    acc[i][j] += a[i] * bb[j];
        }
        __syncthreads();
    }
    float* ob = out + (size_t)b * CC * NPOS;
#pragma unroll
    for (int i = 0; i < 4; ++i) {
        const float4 r = make_float4(acc[i][0], acc[i][1], acc[i][2], acc[i][3]);
        *(float4*)&ob[(size_t)(c0 + trow * 4 + i) * NPOS + j0 + tcol * 4] = r;
    }
}

extern "C" void kernel_launch(void* const* d_in, const int* in_sizes, int n_in,
                              void* d_out, int out_size, void* d_ws, size_t ws_size,
                              hipStream_t stream) {
    const float* fmap    = (const float*)d_in[0];
    const float* gamma   = (const float*)d_in[1];
    const float* w_qk    = (const float*)d_in[2];
    const float* w_v     = (const float*)d_in[3];
    const float* null_kv = (const float*)d_in[4];
    const float* w_out   = (const float*)d_in[5];
    float* out = (float*)d_out;
    float* ws  = (float*)d_ws;
    float* normed = ws;                                  // 2*256*2304 fp32
    u16*   qkh    = (u16*)(normed + 1179648);            // 2*8*2304*64 bf16
    u16*   vtb    = qkh + 2359296;                       // 16*72*64*32 bf16 (frag-ordered)
    float* inner  = (float*)(vtb + 2359296);             // 2*2304*512 fp32
    float* sqbuf  = inner + 2359296;                     // 2*8*2304
    float* ndbuf  = sqbuf + 36864;                       // 2*8*2304
    // total ~ 24 MB

    hipLaunchKernelGGL(k_rmsnorm, dim3(NT, 2),      dim3(256), 0, stream, fmap, gamma, normed);
    hipLaunchKernelGGL(k_proj,    dim3(NT, 16, 2),  dim3(256), 0, stream, normed, w_qk, w_v, null_kv, qkh, vtb, sqbuf, ndbuf);
    hipLaunchKernelGGL(k_attn,    dim3(144, 16),    dim3(256), 0, stream, qkh, vtb, null_kv, sqbuf, ndbuf, inner);
    hipLaunchKernelGGL(k_out,     dim3(NT, 4, 2),   dim3(256), 0, stream, w_out, inner, out);
}

// Round 6
// 265.633 us; speedup vs baseline: 1.4942x; 1.4942x over previous
//
#include <hip/hip_runtime.h>
#include <math.h>

#define NPOS 2304   // 48*48
#define CC   256    // DIM
#define DI   512    // HEADS*DIM_HEAD
#define NT   36     // NPOS/64
#define SCALE 0.125f
#define MASKV -100.0f
// exp(-SCALE*sqrt(d2)) = exp2(-SCALE*log2(e)*sqrt(d2))
#define NEGSL2E (-0.18033688011112042f)

typedef __attribute__((ext_vector_type(8))) short bf16x8;  // 8 bf16 (4 VGPRs)
typedef __attribute__((ext_vector_type(4))) float f32x4;   // MFMA C/D frag
typedef unsigned short u16;
typedef unsigned int u32;

__device__ inline u16 f2bf(float f) {
    union { float f; unsigned int u; } v; v.f = f;
    return (u16)((v.u + 0x7fffu + ((v.u >> 16) & 1u)) >> 16);
}

// ---------------- Kernel 1: ChannelRMSNorm ----------------
__global__ __launch_bounds__(256) void k_rmsnorm(const float* __restrict__ fmap,
                                                 const float* __restrict__ gamma,
                                                 float* __restrict__ normed) {
    const int b  = blockIdx.y;
    const int j0 = blockIdx.x * 64;
    const int tx = threadIdx.x & 63;
    const int ty = threadIdx.x >> 6;
    __shared__ float red[4][64];
    __shared__ float inv[64];
    __shared__ float gs[256];
    gs[threadIdx.x] = gamma[threadIdx.x];
    const float* fb = fmap + (size_t)b * CC * NPOS;
    float s = 0.0f;
#pragma unroll 8
    for (int i = 0; i < 64; ++i) {
        const int c = ty + 4 * i;
        const float v = fb[c * NPOS + j0 + tx];
        s += v * v;
    }
    red[ty][tx] = s;
    __syncthreads();
    if (threadIdx.x < 64) {
        const float t = red[0][tx] + red[1][tx] + red[2][tx] + red[3][tx];
        inv[tx] = 16.0f / fmaxf(sqrtf(t), 1e-12f);
    }
    __syncthreads();
    float* nb = normed + (size_t)b * CC * NPOS;
#pragma unroll 8
    for (int i = 0; i < 64; ++i) {
        const int c = ty + 4 * i;
        nb[c * NPOS + j0 + tx] = fb[c * NPOS + j0 + tx] * inv[tx] * gs[c];
    }
}

// ---------------- Kernel 2: fused qk/v projection GEMM ----------------
// fp32 accumulate; emits bf16 qkh[b,h,n,64] + fp32 sq/ndot, and V in
// MFMA-fragment order: vt[bh][kb32][dim64][32] (kb = key/32, inner = quad*8+j).
__global__ __launch_bounds__(256) void k_proj(const float* __restrict__ normed,
                                              const float* __restrict__ w_qk,
                                              const float* __restrict__ w_v,
                                              const float* __restrict__ null_kv,
                                              u16* __restrict__ qkh,
                                              u16* __restrict__ vt,
                                              float* __restrict__ sq,
                                              float* __restrict__ ndot) {
    const int b  = blockIdx.z;
    const int o0 = blockIdx.y * 64;   // 0..1023
    const int j0 = blockIdx.x * 64;
    const int t  = threadIdx.x;
    const int trow = t >> 4, tcol = t & 15;
    __shared__ float Ast[16][68];   // Ast[k][o]
    __shared__ float Bs[16][68];    // Bs[k][j]
    __shared__ u16 Tt[64][72];      // bf16 transpose staging [j][d]
    __shared__ float nks[64];
    float acc[4][4] = {};
    const float* W = (o0 < DI) ? w_qk : w_v;
    const int or0 = (o0 < DI) ? o0 : (o0 - DI);
    const int h = or0 >> 6;
    if (o0 < DI && t < 64) nks[t] = null_kv[h * 64 + t];
    const float* nbp = normed + (size_t)b * CC * NPOS;
    for (int k0 = 0; k0 < 256; k0 += 16) {
        {
            const int o = t >> 2, kq = t & 3;
            const float4 w4 = *(const float4*)&W[(or0 + o) * 256 + k0 + kq * 4];
            Ast[kq * 4 + 0][o] = w4.x; Ast[kq * 4 + 1][o] = w4.y;
            Ast[kq * 4 + 2][o] = w4.z; Ast[kq * 4 + 3][o] = w4.w;
        }
        {
            const int kk = t >> 4, jq = t & 15;
            const float4 b4 = *(const float4*)&nbp[(k0 + kk) * NPOS + j0 + jq * 4];
            *(float4*)&Bs[kk][jq * 4] = b4;
        }
        __syncthreads();
#pragma unroll
        for (int kk = 0; kk < 16; ++kk) {
            const float4 a4 = *(const float4*)&Ast[kk][trow * 4];
            const float4 b4 = *(const float4*)&Bs[kk][tcol * 4];
            const float a[4]  = {a4.x, a4.y, a4.z, a4.w};
            const float bb[4] = {b4.x, b4.y, b4.z, b4.w};
#pragma unroll
            for (int i = 0; i < 4; ++i)
#pragma unroll
                for (int j = 0; j < 4; ++j)
                    acc[i][j] += a[i] * bb[j];
        }
        __syncthreads();
    }
    if (o0 < DI) {
        float sjj[4], njj[4];
#pragma unroll
        for (int jj = 0; jj < 4; ++jj) {
            float ts = 0.0f, tn = 0.0f;
#pragma unroll
            for (int i = 0; i < 4; ++i) {
                ts += acc[i][jj] * acc[i][jj];
                tn += acc[i][jj] * nks[trow * 4 + i];
            }
            sjj[jj] = ts; njj[jj] = tn;
        }
        *(float4*)&Ast[trow][tcol * 4] = make_float4(sjj[0], sjj[1], sjj[2], sjj[3]);
        *(float4*)&Bs[trow][tcol * 4]  = make_float4(njj[0], njj[1], njj[2], njj[3]);
#pragma unroll
        for (int i = 0; i < 4; ++i)
#pragma unroll
            for (int jj = 0; jj < 4; ++jj)
                Tt[tcol * 4 + jj][trow * 4 + i] = f2bf(acc[i][jj]);
        __syncthreads();
        if (t < 64) {
            float s = 0.0f, n = 0.0f;
#pragma unroll
            for (int r = 0; r < 16; ++r) { s += Ast[r][t]; n += Bs[r][t]; }
            sq  [((size_t)b * 8 + h) * NPOS + j0 + t] = s;
            ndot[((size_t)b * 8 + h) * NPOS + j0 + t] = n;
        }
        const int row = t >> 2, seg = t & 3;
        const int4 w0 = *(const int4*)&Tt[row][seg * 16];
        const int4 w1 = *(const int4*)&Tt[row][seg * 16 + 8];
        u16* dst = qkh + (((size_t)b * 8 + h) * NPOS + j0 + row) * 64 + seg * 16;
        *(int4*)&dst[0] = w0;
        *(int4*)&dst[8] = w1;
    } else {
        // V: fragment-ordered store vt[bh][kb][d][quad*8 + j]
        const size_t vb_base = (size_t)(b * 8 + h) * (72 * 64 * 32);
        const int kb   = (j0 >> 5) + (tcol >> 3);
        const int quad = (tcol >> 1) & 3;
        const int joff = (tcol & 1) * 4;
#pragma unroll
        for (int i = 0; i < 4; ++i) {
            const int d = trow * 4 + i;
            ushort4 r4;
            r4.x = f2bf(acc[i][0]); r4.y = f2bf(acc[i][1]);
            r4.z = f2bf(acc[i][2]); r4.w = f2bf(acc[i][3]);
            *(ushort4*)&vt[vb_base + ((size_t)kb * 64 + d) * 32 + quad * 8 + joff] = r4;
        }
    }
}

// ---------------- Kernel 3: K-split MFMA flash attention ----------------
// 4 waves/block on the same 16 queries; wave w covers K-tiles [9w, 9w+9).
// Single-buffered frag loads (NO runtime-indexed arrays -> no scratch spill);
// m=0 fixed softmax makes O and l key-linear -> exact LDS partial merge.
__global__ __launch_bounds__(256) void k_attn(const u16* __restrict__ qkh,
                                              const u16* __restrict__ vt,
                                              const float* __restrict__ null_kv,
                                              const float* __restrict__ sq,
                                              const float* __restrict__ ndot,
                                              float* __restrict__ inner) {
    const int q16 = blockIdx.x * 16;            // 144 query tiles of 16
    const int bh = blockIdx.y;
    const int b = bh >> 3, h = bh & 7;
    const int t = threadIdx.x;
    const int wave = t >> 6, lane = t & 63;
    const int mcol = lane & 15, quad = lane >> 4;

    // union: per-wave Pt[16][72] u16 (4x2304B) || reduction buf float[256][18]
    __shared__ __align__(16) char smem[18432];
    u16 (*Pt)[72] = (u16(*)[72])(smem + wave * 2304);

    const u16* qbase = qkh + (size_t)bh * NPOS * 64;
    const u16* vbase = vt + (size_t)bh * (72 * 64 * 32);
    const float* sqb = sq + (size_t)bh * NPOS;

    // Q B-frags: n = query = mcol, contraction = d (two K=32 chunks)
    const bf16x8 bq0 = *(const bf16x8*)&qbase[(q16 + mcol) * 64 + quad * 8];
    const bf16x8 bq1 = *(const bf16x8*)&qbase[(q16 + mcol) * 64 + 32 + quad * 8];
    const float q2 = sqb[q16 + mcol];

    const bf16x8 ones = {0x3F80, 0x3F80, 0x3F80, 0x3F80, 0x3F80, 0x3F80, 0x3F80, 0x3F80};
    const int ktm = q16 >> 6, nbm = (q16 >> 4) & 3;

    f32x4 oacc[4];
#pragma unroll
    for (int nb = 0; nb < 4; ++nb) oacc[nb] = (f32x4){0.f, 0.f, 0.f, 0.f};
    f32x4 lsum = (f32x4){0.f, 0.f, 0.f, 0.f};

    const int kt0 = wave * 9;

#pragma unroll 3
    for (int kt9 = 0; kt9 < 9; ++kt9) {
        const int kt = kt0 + kt9;
        const int kj0 = kt * 64;

        // ---- all loads first (vmcnt overlaps across unroll + waves) ----
        bf16x8 bk[4][2], bv[4][2];
#pragma unroll
        for (int nb = 0; nb < 4; ++nb) {
            const u16* kr = &qbase[(kj0 + nb * 16 + mcol) * 64 + quad * 8];
            bk[nb][0] = *(const bf16x8*)&kr[0];
            bk[nb][1] = *(const bf16x8*)&kr[32];
        }
#pragma unroll
        for (int nb = 0; nb < 4; ++nb) {
            bv[nb][0] = *(const bf16x8*)&vbase[((size_t)(kt * 2 + 0) * 64 + nb * 16 + mcol) * 32 + quad * 8];
            bv[nb][1] = *(const bf16x8*)&vbase[((size_t)(kt * 2 + 1) * 64 + nb * 16 + mcol) * 32 + quad * 8];
        }
        float4 k2q[4];
#pragma unroll
        for (int nb = 0; nb < 4; ++nb)
            k2q[nb] = *(const float4*)&sqb[kj0 + nb * 16 + quad * 4];

        // S^T = K.Q^T
        f32x4 c[4];
#pragma unroll
        for (int nb = 0; nb < 4; ++nb) {
            c[nb] = (f32x4){0.f, 0.f, 0.f, 0.f};
            c[nb] = __builtin_amdgcn_mfma_f32_16x16x32_bf16(bk[nb][0], bq0, c[nb], 0, 0, 0);
            c[nb] = __builtin_amdgcn_mfma_f32_16x16x32_bf16(bk[nb][1], bq1, c[nb], 0, 0, 0);
        }

        // softmax numerator: e = exp2(-c1*sqrt(max(q2+k2-2*qk, 0))), m = 0 fixed
#pragma unroll
        for (int nb = 0; nb < 4; ++nb) {
            float e[4];
#pragma unroll
            for (int r = 0; r < 4; ++r) {
                const float pre = q2 + ((const float*)&k2q[nb])[r];
                const float d2 = fmaxf(__builtin_fmaf(c[nb][r], -2.0f, pre), 0.0f);
                e[r] = __builtin_amdgcn_exp2f(NEGSL2E * __builtin_amdgcn_sqrtf(d2));
            }
            if (kt == ktm && nb == nbm) {
#pragma unroll
                for (int r = 0; r < 4; ++r)
                    if (quad * 4 + r == mcol) e[r] = 0.0f;   // exp(MASKV) ~ 0
            }
            const u32 p01 = __builtin_amdgcn_perm(__float_as_uint(e[1]), __float_as_uint(e[0]), 0x07060302u);
            const u32 p23 = __builtin_amdgcn_perm(__float_as_uint(e[3]), __float_as_uint(e[2]), 0x07060302u);
            *(uint2*)&Pt[mcol][nb * 16 + quad * 4] = make_uint2(p01, p23);
        }

        // P^T B-frags (wave-private LDS; in-wave DS ordering, no barrier)
        const bf16x8 bp0 = *(const bf16x8*)&Pt[mcol][quad * 8];
        const bf16x8 bp1 = *(const bf16x8*)&Pt[mcol][32 + quad * 8];

#pragma unroll
        for (int nb = 0; nb < 4; ++nb) {
            oacc[nb] = __builtin_amdgcn_mfma_f32_16x16x32_bf16(bv[nb][0], bp0, oacc[nb], 0, 0, 0);
            oacc[nb] = __builtin_amdgcn_mfma_f32_16x16x32_bf16(bv[nb][1], bp1, oacc[nb], 0, 0, 0);
        }
        lsum = __builtin_amdgcn_mfma_f32_16x16x32_bf16(ones, bp0, lsum, 0, 0, 0);
        lsum = __builtin_amdgcn_mfma_f32_16x16x32_bf16(ones, bp1, lsum, 0, 0, 0);
    }

    // ---- cross-wave reduction (O and l are key-linear: exact merge) ----
    __syncthreads();   // all waves done reading their Pt before aliasing as Ored
    float* my = (float*)smem + (size_t)t * 18;
#pragma unroll
    for (int nb = 0; nb < 4; ++nb)
#pragma unroll
        for (int r = 0; r < 4; ++r) my[nb * 4 + r] = oacc[nb][r];
    my[16] = lsum[0];
    __syncthreads();

    if (wave == 0) {
        float o[16], l = 0.0f;
#pragma unroll
        for (int i = 0; i < 16; ++i) o[i] = 0.0f;
#pragma unroll
        for (int w = 0; w < 4; ++w) {
            const float* src = (const float*)smem + (size_t)(w * 64 + lane) * 18;
#pragma unroll
            for (int i = 0; i < 16; ++i) o[i] += src[i];
            l += src[16];
        }
        // null key/value epilogue (m=0: beta = exp(sim_null))
        float nk2 = 0.0f;
#pragma unroll 8
        for (int d = 0; d < 64; ++d) { const float nk = null_kv[h * 64 + d]; nk2 += nk * nk; }
        const float nd = ndot[(size_t)bh * NPOS + q16 + mcol];
        const float d2n = fmaxf(q2 + nk2 - 2.0f * nd, 0.0f);
        const float beta = __expf(-sqrtf(d2n) * SCALE);
        const float il = 1.0f / (l + beta);

        float* ob = inner + ((size_t)b * NPOS + q16 + mcol) * DI + h * 64;
#pragma unroll
        for (int nb = 0; nb < 4; ++nb) {
            const float4 nv4 = *(const float4*)&null_kv[DI + h * 64 + nb * 16 + quad * 4];
            float4 r;
            r.x = (o[nb * 4 + 0] + beta * nv4.x) * il;
            r.y = (o[nb * 4 + 1] + beta * nv4.y) * il;
            r.z = (o[nb * 4 + 2] + beta * nv4.z) * il;
            r.w = (o[nb * 4 + 3] + beta * nv4.w) * il;
            *(float4*)&ob[nb * 16 + quad * 4] = r;
        }
    }
}

// ---------------- Kernel 4: output projection ----------------
__global__ __launch_bounds__(256) void k_out(const float* __restrict__ w_out,
                                             const float* __restrict__ inner,
                                             float* __restrict__ out) {
    const int b  = blockIdx.z;
    const int c0 = blockIdx.y * 64;
    const int j0 = blockIdx.x * 64;
    const int t  = threadIdx.x;
    const int trow = t >> 4, tcol = t & 15;
    __shared__ float Ast[16][68];  // Ast[k][c]
    __shared__ float Bst[16][68];  // Bst[k][j]
    float acc[4][4] = {};
    const float* ib = inner + (size_t)b * NPOS * DI;
    for (int k0 = 0; k0 < 512; k0 += 16) {
        {
            const int cr = t >> 2, kq = t & 3;
            const float4 w4 = *(const float4*)&w_out[(c0 + cr) * DI + k0 + kq * 4];
            Ast[kq * 4 + 0][cr] = w4.x; Ast[kq * 4 + 1][cr] = w4.y;
            Ast[kq * 4 + 2][cr] = w4.z; Ast[kq * 4 + 3][cr] = w4.w;
        }
        {
            const int jr = t >> 2, kq = t & 3;
            const float4 i4 = *(const float4*)&ib[(size_t)(j0 + jr) * DI + k0 + kq * 4];
            Bst[kq * 4 + 0][jr] = i4.x; Bst[kq * 4 + 1][jr] = i4.y;
            Bst[kq * 4 + 2][jr] = i4.z; Bst[kq * 4 + 3][jr] = i4.w;
        }
        __syncthreads();
#pragma unroll
        for (int kk = 0; kk < 16; ++kk) {
            const float4 a4 = *(const float4*)&Ast[kk][trow * 4];
            const float4 b4 = *(const float4*)&Bst[kk][tcol * 4];
            const float a[4]  = {a4.x, a4.y, a4.z, a4.w};
            const float bb[4] = {b4.x, b4.y, b4.z, b4.w};
#pragma unroll
            for (int i = 0; i < 4; ++i)
#pragma unroll
                for (int j = 0; j < 4; ++j)
                    acc[i][j] += a[i] * bb[j];
        }
        __syncthreads();
    }
    float* ob = out + (size_t)b * CC * NPOS;
#pragma unroll
    for (int i = 0; i < 4; ++i) {
        const float4 r = make_float4(acc[i][0], acc[i][1], acc[i][2], acc[i][3]);
        *(float4*)&ob[(size_t)(c0 + trow * 4 + i) * NPOS + j0 + tcol * 4] = r;
    }
}

extern "C" void kernel_launch(void* const* d_in, const int* in_sizes, int n_in,
                              void* d_out, int out_size, void* d_ws, size_t ws_size,
                              hipStream_t stream) {
    const float* fmap    = (const float*)d_in[0];
    const float* gamma   = (const float*)d_in[1];
    const float* w_qk    = (const float*)d_in[2];
    const float* w_v     = (const float*)d_in[3];
    const float* null_kv = (const float*)d_in[4];
    const float* w_out   = (const float*)d_in[5];
    float* out = (float*)d_out;
    float* ws  = (float*)d_ws;
    float* normed = ws;                                  // 2*256*2304 fp32
    u16*   qkh    = (u16*)(normed + 1179648);            // 2*8*2304*64 bf16
    u16*   vtb    = qkh + 2359296;                       // 16*72*64*32 bf16 (frag-ordered)
    float* inner  = (float*)(vtb + 2359296);             // 2*2304*512 fp32
    float* sqbuf  = inner + 2359296;                     // 2*8*2304
    float* ndbuf  = sqbuf + 36864;                       // 2*8*2304
    // total ~ 24 MB

    hipLaunchKernelGGL(k_rmsnorm, dim3(NT, 2),      dim3(256), 0, stream, fmap, gamma, normed);
    hipLaunchKernelGGL(k_proj,    dim3(NT, 16, 2),  dim3(256), 0, stream, normed, w_qk, w_v, null_kv, qkh, vtb, sqbuf, ndbuf);
    hipLaunchKernelGGL(k_attn,    dim3(144, 16),    dim3(256), 0, stream, qkh, vtb, null_kv, sqbuf, ndbuf, inner);
    hipLaunchKernelGGL(k_out,     dim3(NT, 4, 2),   dim3(256), 0, stream, w_out, inner, out);
}

// Round 7
// 262.529 us; speedup vs baseline: 1.5119x; 1.0118x over previous
//
#include <hip/hip_runtime.h>
#include <math.h>

#define NPOS 2304   // 48*48
#define CC   256    // DIM
#define DI   512    // HEADS*DIM_HEAD
#define NT   36     // NPOS/64
#define SCALE 0.125f
#define MASKV -100.0f
// exp(-SCALE*sqrt(d2)) = exp2(-SCALE*log2(e)*sqrt(d2))
#define NEGSL2E (-0.18033688011112042f)

typedef __attribute__((ext_vector_type(8))) short bf16x8;  // 8 bf16 (4 VGPRs)
typedef __attribute__((ext_vector_type(4))) float f32x4;   // MFMA C/D frag
typedef unsigned short u16;
typedef unsigned int u32;

__device__ inline u16 f2bf(float f) {
    union { float f; unsigned int u; } v; v.f = f;
    return (u16)((v.u + 0x7fffu + ((v.u >> 16) & 1u)) >> 16);
}
__device__ inline float bf2f(u16 h) { return __uint_as_float(((u32)h) << 16); }

// ---------------- Kernel 1: ChannelRMSNorm -> bf16 X[b][n][c] ----------------
// Reads fmap [c][n] coalesced; LDS transpose (pitch 258 u16: bank-free writes);
// writes Xb[b][n][256] bf16 fully coalesced.
__global__ __launch_bounds__(256) void k_prep(const float* __restrict__ fmap,
                                              const float* __restrict__ gamma,
                                              u16* __restrict__ xb) {
    const int b  = blockIdx.y;
    const int j0 = blockIdx.x * 64;
    const int tx = threadIdx.x & 63;
    const int ty = threadIdx.x >> 6;
    __shared__ u16 X[64][258];      // [n][c], pitch 258 -> dword pitch 129 (==1 mod 32)
    __shared__ float red[4][64];
    __shared__ float inv[64];
    __shared__ float gs[256];
    gs[threadIdx.x] = gamma[threadIdx.x];
    const float* fb = fmap + (size_t)b * CC * NPOS;
    float s = 0.0f;
#pragma unroll 8
    for (int i = 0; i < 64; ++i) {
        const int c = ty * 64 + i;
        const float v = fb[c * NPOS + j0 + tx];
        s += v * v;
    }
    red[ty][tx] = s;
    __syncthreads();
    if (threadIdx.x < 64) {
        const float t = red[0][tx] + red[1][tx] + red[2][tx] + red[3][tx];
        inv[tx] = 16.0f / fmaxf(sqrtf(t), 1e-12f);
    }
    __syncthreads();
    const float iv = inv[tx];
#pragma unroll 4
    for (int i = 0; i < 64; i += 2) {
        const int c = ty * 64 + i;
        const float v0 = fb[c * NPOS + j0 + tx] * iv * gs[c];
        const float v1 = fb[(c + 1) * NPOS + j0 + tx] * iv * gs[c + 1];
        const u32 pk = (u32)f2bf(v0) | ((u32)f2bf(v1) << 16);
        *(u32*)&X[tx][c] = pk;   // dword bank = tx + c/2 -> 2-way max (free)
    }
    __syncthreads();
    // coalesced writeout: wave w handles rows w*16..+15; lane covers 4 u16
    const int w = ty;
    u16* xdst = xb + ((size_t)b * NPOS + j0) * 256;
#pragma unroll
    for (int i = 0; i < 16; ++i) {
        const int n = w * 16 + i;
        const u32 a = *(const u32*)&X[n][tx * 4];
        const u32 c2 = *(const u32*)&X[n][tx * 4 + 2];
        *(uint2*)&xdst[(size_t)n * 256 + tx * 4] = make_uint2(a, c2);
    }
}

// ---------------- Kernel 1b: weight conversion ----------------
// wb = bf16 concat(w_qk, w_v) [1024][256]; w_out split hi/lo bf16 [256][512];
// nk2b[h] = |null_k_h|^2 (fp32).
__global__ __launch_bounds__(256) void k_wcvt(const float* __restrict__ wqk,
                                              const float* __restrict__ wv,
                                              const float* __restrict__ wout,
                                              const float* __restrict__ nkv,
                                              u16* __restrict__ wb,
                                              u16* __restrict__ wo_hi,
                                              u16* __restrict__ wo_lo,
                                              float* __restrict__ nk2b) {
    const int tid = blockIdx.x * 256 + threadIdx.x;
    if (tid < 32768) {
        const float4 v = ((const float4*)wqk)[tid];
        ushort4 r; r.x = f2bf(v.x); r.y = f2bf(v.y); r.z = f2bf(v.z); r.w = f2bf(v.w);
        ((ushort4*)wb)[tid] = r;
    } else if (tid < 65536) {
        const float4 v = ((const float4*)wv)[tid - 32768];
        ushort4 r; r.x = f2bf(v.x); r.y = f2bf(v.y); r.z = f2bf(v.z); r.w = f2bf(v.w);
        ((ushort4*)wb)[tid] = r;   // [32768..65536) maps to wb offset 131072+
    } else {
        const int k = tid - 65536;
        const float4 v = ((const float4*)wout)[k];
        ushort4 h, l;
        h.x = f2bf(v.x); l.x = f2bf(v.x - bf2f(h.x));
        h.y = f2bf(v.y); l.y = f2bf(v.y - bf2f(h.y));
        h.z = f2bf(v.z); l.z = f2bf(v.z - bf2f(h.z));
        h.w = f2bf(v.w); l.w = f2bf(v.w - bf2f(h.w));
        ((ushort4*)wo_hi)[k] = h;
        ((ushort4*)wo_lo)[k] = l;
    }
    if (blockIdx.x == 0 && threadIdx.x < 8) {
        float s = 0.0f;
#pragma unroll 8
        for (int d = 0; d < 64; ++d) { const float x = nkv[threadIdx.x * 64 + d]; s += x * x; }
        nk2b[threadIdx.x] = s;
    }
}

// ---------------- Kernel 2: MFMA qk/v projection ----------------
// C[o 64][n 64] per block = Wb x Xb (bf16 MFMA, fp32 acc). Wave w owns o-rows
// [w*16, w*16+16). qk half (oy<8): emits qkh[bh][n][64] via LDS transpose +
// fp32 sq/ndot from accum. v half: emits vt frag-ordered [bh][kb32][d][32].
__global__ __launch_bounds__(256) void k_proj(const u16* __restrict__ xb,
                                              const u16* __restrict__ wb,
                                              const float* __restrict__ null_kv,
                                              u16* __restrict__ qkh,
                                              u16* __restrict__ vt,
                                              float* __restrict__ sq,
                                              float* __restrict__ ndot) {
    const int n0 = blockIdx.x * 64;
    const int oy = blockIdx.y;            // 0..15; o0 = oy*64
    const int b  = blockIdx.z;
    const int t  = threadIdx.x;
    const int w = t >> 6, lane = t & 63, mcol = lane & 15, quad = lane >> 4;
    __shared__ u16 Tt[64][68];
    __shared__ float sqp[4][64], ndp[4][64];

    const u16* wrow = wb + (size_t)(oy * 64 + w * 16 + mcol) * 256 + quad * 8;
    const u16* xrow = xb + ((size_t)b * NPOS + n0 + mcol) * 256 + quad * 8;

    f32x4 c[4];
#pragma unroll
    for (int nf = 0; nf < 4; ++nf) c[nf] = (f32x4){0.f, 0.f, 0.f, 0.f};
#pragma unroll
    for (int kc = 0; kc < 8; ++kc) {
        const bf16x8 a = *(const bf16x8*)&wrow[kc * 32];
        bf16x8 xB[4];
#pragma unroll
        for (int nf = 0; nf < 4; ++nf)
            xB[nf] = *(const bf16x8*)&xrow[(size_t)nf * 16 * 256 + kc * 32];
#pragma unroll
        for (int nf = 0; nf < 4; ++nf)
            c[nf] = __builtin_amdgcn_mfma_f32_16x16x32_bf16(a, xB[nf], c[nf], 0, 0, 0);
    }

    if (oy < 8) {
        const int h = oy;   // d = w*16 + quad*4 + r, n = n0 + nf*16 + mcol
        const float4 nk4 = *(const float4*)&null_kv[h * 64 + w * 16 + quad * 4];
        float s[4], nd[4];
#pragma unroll
        for (int nf = 0; nf < 4; ++nf) {
            s[nf]  = c[nf][0] * c[nf][0] + c[nf][1] * c[nf][1] + c[nf][2] * c[nf][2] + c[nf][3] * c[nf][3];
            nd[nf] = c[nf][0] * nk4.x + c[nf][1] * nk4.y + c[nf][2] * nk4.z + c[nf][3] * nk4.w;
        }
#pragma unroll
        for (int mk = 16; mk <= 32; mk <<= 1)
#pragma unroll
            for (int nf = 0; nf < 4; ++nf) {
                s[nf]  += __shfl_xor(s[nf], mk);
                nd[nf] += __shfl_xor(nd[nf], mk);
            }
        if (quad == 0) {
#pragma unroll
            for (int nf = 0; nf < 4; ++nf) {
                sqp[w][nf * 16 + mcol] = s[nf];
                ndp[w][nf * 16 + mcol] = nd[nf];
            }
        }
#pragma unroll
        for (int nf = 0; nf < 4; ++nf) {
            ushort4 r4;
            r4.x = f2bf(c[nf][0]); r4.y = f2bf(c[nf][1]);
            r4.z = f2bf(c[nf][2]); r4.w = f2bf(c[nf][3]);
            *(ushort4*)&Tt[nf * 16 + mcol][w * 16 + quad * 4] = r4;   // Tt[n][d]
        }
        __syncthreads();
        {   // readback: row n, 16 u16 of d per thread -> coalesced dwordx4 x2
            const int n = t >> 2, ds = (t & 3) * 16;
            const uint2 r0 = *(const uint2*)&Tt[n][ds + 0];
            const uint2 r1 = *(const uint2*)&Tt[n][ds + 4];
            const uint2 r2 = *(const uint2*)&Tt[n][ds + 8];
            const uint2 r3 = *(const uint2*)&Tt[n][ds + 12];
            u16* dst = qkh + (((size_t)b * 8 + h) * NPOS + n0 + n) * 64 + ds;
            *(uint4*)&dst[0] = make_uint4(r0.x, r0.y, r1.x, r1.y);
            *(uint4*)&dst[8] = make_uint4(r2.x, r2.y, r3.x, r3.y);
        }
        if (t < 64) {
            sq  [((size_t)b * 8 + h) * NPOS + n0 + t] = sqp[0][t] + sqp[1][t] + sqp[2][t] + sqp[3][t];
            ndot[((size_t)b * 8 + h) * NPOS + n0 + t] = ndp[0][t] + ndp[1][t] + ndp[2][t] + ndp[3][t];
        }
    } else {
        const int h = oy - 8;   // d = w*16+quad*4+r, key = n0 + nf*16 + mcol
#pragma unroll
        for (int nf = 0; nf < 4; ++nf)
#pragma unroll
            for (int r = 0; r < 4; ++r)
                Tt[w * 16 + quad * 4 + r][nf * 16 + mcol] = f2bf(c[nf][r]);  // Tt[d][key]
        __syncthreads();
        {   // readback: row d, 16 keys per thread -> vt frag order
            const int d = t >> 2, ks = t & 3;
            const uint2 a0 = *(const uint2*)&Tt[d][ks * 16 + 0];
            const uint2 a1 = *(const uint2*)&Tt[d][ks * 16 + 4];
            const uint2 a2 = *(const uint2*)&Tt[d][ks * 16 + 8];
            const uint2 a3 = *(const uint2*)&Tt[d][ks * 16 + 12];
            u16* vdst = vt + (size_t)(b * 8 + h) * (72 * 64 * 32);
            const int kb = blockIdx.x * 2 + (ks >> 1);
            u16* p = &vdst[((size_t)kb * 64 + d) * 32 + (ks & 1) * 16];
            *(uint4*)&p[0] = make_uint4(a0.x, a0.y, a1.x, a1.y);
            *(uint4*)&p[8] = make_uint4(a2.x, a2.y, a3.x, a3.y);
        }
    }
}

// ---------------- Kernel 3: K-split MFMA flash attention (pipelined) ----------------
// 4 waves/block on the same 16 queries; wave w covers K-tiles [9w, 9w+9).
// Explicitly-named 2-deep K-frag pipeline (no runtime-indexed arrays!).
// m=0 fixed softmax; emits inner as split hi/lo bf16 [b][n][512].
__global__ __launch_bounds__(256) void k_attn(const u16* __restrict__ qkh,
                                              const u16* __restrict__ vt,
                                              const float* __restrict__ null_kv,
                                              const float* __restrict__ nk2b,
                                              const float* __restrict__ sq,
                                              const float* __restrict__ ndot,
                                              u16* __restrict__ inner_hi,
                                              u16* __restrict__ inner_lo) {
    const int q16 = blockIdx.x * 16;
    const int bh = blockIdx.y;
    const int b = bh >> 3, h = bh & 7;
    const int t = threadIdx.x;
    const int wave = t >> 6, lane = t & 63;
    const int mcol = lane & 15, quad = lane >> 4;

    __shared__ __align__(16) char smem[18432];  // per-wave Pt[16][72] || float[256][18]
    u16 (*Pt)[72] = (u16(*)[72])(smem + wave * 2304);

    const u16* qbase = qkh + (size_t)bh * NPOS * 64;
    const u16* vbase = vt + (size_t)bh * (72 * 64 * 32);
    const float* sqb = sq + (size_t)bh * NPOS;

    const bf16x8 bq0 = *(const bf16x8*)&qbase[(q16 + mcol) * 64 + quad * 8];
    const bf16x8 bq1 = *(const bf16x8*)&qbase[(q16 + mcol) * 64 + 32 + quad * 8];
    const float q2 = sqb[q16 + mcol];

    const bf16x8 ones = {0x3F80, 0x3F80, 0x3F80, 0x3F80, 0x3F80, 0x3F80, 0x3F80, 0x3F80};
    const int ktm = q16 >> 6, nbm = (q16 >> 4) & 3;

    f32x4 oacc[4];
#pragma unroll
    for (int nb = 0; nb < 4; ++nb) oacc[nb] = (f32x4){0.f, 0.f, 0.f, 0.f};
    f32x4 lsum = (f32x4){0.f, 0.f, 0.f, 0.f};

    const int kt0 = wave * 9;

    auto loadK = [&](bf16x8 (&bk)[4][2], float4 (&k2)[4], int kt) {
        const int kj0 = kt * 64;
#pragma unroll
        for (int nb = 0; nb < 4; ++nb) {
            const u16* kr = &qbase[(kj0 + nb * 16 + mcol) * 64 + quad * 8];
            bk[nb][0] = *(const bf16x8*)&kr[0];
            bk[nb][1] = *(const bf16x8*)&kr[32];
            k2[nb] = *(const float4*)&sqb[kj0 + nb * 16 + quad * 4];
        }
    };
    auto body = [&](const bf16x8 (&bk)[4][2], const float4 (&k2q)[4], int kt) {
        const int kj0 = kt * 64;
        // V A-frags (single-buffered; needed only after exp -> latency covered)
        bf16x8 bv[4][2];
#pragma unroll
        for (int nb = 0; nb < 4; ++nb) {
            bv[nb][0] = *(const bf16x8*)&vbase[((size_t)(kt * 2 + 0) * 64 + nb * 16 + mcol) * 32 + quad * 8];
            bv[nb][1] = *(const bf16x8*)&vbase[((size_t)(kt * 2 + 1) * 64 + nb * 16 + mcol) * 32 + quad * 8];
        }
        f32x4 c[4];
#pragma unroll
        for (int nb = 0; nb < 4; ++nb) {
            c[nb] = (f32x4){0.f, 0.f, 0.f, 0.f};
            c[nb] = __builtin_amdgcn_mfma_f32_16x16x32_bf16(bk[nb][0], bq0, c[nb], 0, 0, 0);
            c[nb] = __builtin_amdgcn_mfma_f32_16x16x32_bf16(bk[nb][1], bq1, c[nb], 0, 0, 0);
        }
#pragma unroll
        for (int nb = 0; nb < 4; ++nb) {
            float e[4];
#pragma unroll
            for (int r = 0; r < 4; ++r) {
                const float pre = q2 + ((const float*)&k2q[nb])[r];
                const float d2 = fmaxf(__builtin_fmaf(c[nb][r], -2.0f, pre), 0.0f);
                e[r] = __builtin_amdgcn_exp2f(NEGSL2E * __builtin_amdgcn_sqrtf(d2));
            }
            if (kt == ktm && nb == nbm) {
#pragma unroll
                for (int r = 0; r < 4; ++r)
                    if (quad * 4 + r == mcol) e[r] = 0.0f;   // exp(MASKV) ~ 0
            }
            const u32 p01 = __builtin_amdgcn_perm(__float_as_uint(e[1]), __float_as_uint(e[0]), 0x07060302u);
            const u32 p23 = __builtin_amdgcn_perm(__float_as_uint(e[3]), __float_as_uint(e[2]), 0x07060302u);
            *(uint2*)&Pt[mcol][nb * 16 + quad * 4] = make_uint2(p01, p23);
        }
        const bf16x8 bp0 = *(const bf16x8*)&Pt[mcol][quad * 8];
        const bf16x8 bp1 = *(const bf16x8*)&Pt[mcol][32 + quad * 8];
#pragma unroll
        for (int nb = 0; nb < 4; ++nb) {
            oacc[nb] = __builtin_amdgcn_mfma_f32_16x16x32_bf16(bv[nb][0], bp0, oacc[nb], 0, 0, 0);
            oacc[nb] = __builtin_amdgcn_mfma_f32_16x16x32_bf16(bv[nb][1], bp1, oacc[nb], 0, 0, 0);
        }
        lsum = __builtin_amdgcn_mfma_f32_16x16x32_bf16(ones, bp0, lsum, 0, 0, 0);
        lsum = __builtin_amdgcn_mfma_f32_16x16x32_bf16(ones, bp1, lsum, 0, 0, 0);
    };

    // 2-deep pipeline, explicit A/B register sets, 9 tiles (8 paired + tail)
    bf16x8 bkA[4][2], bkB[4][2];
    float4 k2A[4], k2B[4];
    loadK(bkA, k2A, kt0);
#pragma unroll
    for (int p = 0; p < 4; ++p) {
        loadK(bkB, k2B, kt0 + 2 * p + 1);
        body(bkA, k2A, kt0 + 2 * p);
        loadK(bkA, k2A, kt0 + 2 * p + 2);
        body(bkB, k2B, kt0 + 2 * p + 1);
    }
    body(bkA, k2A, kt0 + 8);

    // ---- cross-wave reduction (O and l are key-linear: exact merge) ----
    __syncthreads();
    float* my = (float*)smem + (size_t)t * 18;
#pragma unroll
    for (int nb = 0; nb < 4; ++nb)
#pragma unroll
        for (int r = 0; r < 4; ++r) my[nb * 4 + r] = oacc[nb][r];
    my[16] = lsum[0];
    __syncthreads();

    if (wave == 0) {
        float o[16], l = 0.0f;
#pragma unroll
        for (int i = 0; i < 16; ++i) o[i] = 0.0f;
#pragma unroll
        for (int w = 0; w < 4; ++w) {
            const float* src = (const float*)smem + (size_t)(w * 64 + lane) * 18;
#pragma unroll
            for (int i = 0; i < 16; ++i) o[i] += src[i];
            l += src[16];
        }
        const float nk2 = nk2b[h];
        const float nd = ndot[(size_t)bh * NPOS + q16 + mcol];
        const float d2n = fmaxf(q2 + nk2 - 2.0f * nd, 0.0f);
        const float beta = __expf(-sqrtf(d2n) * SCALE);
        const float il = 1.0f / (l + beta);

        const size_t obase = ((size_t)b * NPOS + q16 + mcol) * DI + h * 64;
#pragma unroll
        for (int nb = 0; nb < 4; ++nb) {
            const float4 nv4 = *(const float4*)&null_kv[DI + h * 64 + nb * 16 + quad * 4];
            float v[4];
            v[0] = (o[nb * 4 + 0] + beta * nv4.x) * il;
            v[1] = (o[nb * 4 + 1] + beta * nv4.y) * il;
            v[2] = (o[nb * 4 + 2] + beta * nv4.z) * il;
            v[3] = (o[nb * 4 + 3] + beta * nv4.w) * il;
            ushort4 hi4, lo4;
            hi4.x = f2bf(v[0]); lo4.x = f2bf(v[0] - bf2f(hi4.x));
            hi4.y = f2bf(v[1]); lo4.y = f2bf(v[1] - bf2f(hi4.y));
            hi4.z = f2bf(v[2]); lo4.z = f2bf(v[2] - bf2f(hi4.z));
            hi4.w = f2bf(v[3]); lo4.w = f2bf(v[3] - bf2f(hi4.w));
            *(ushort4*)&inner_hi[obase + nb * 16 + quad * 4] = hi4;
            *(ushort4*)&inner_lo[obase + nb * 16 + quad * 4] = lo4;
        }
    }
}

// ---------------- Kernel 4: output projection (split-bf16 MFMA) ----------------
// out[c][j] = w_out . inner ; 3-term split (hi*hi + hi*lo + lo*hi), fp32 acc.
__global__ __launch_bounds__(256) void k_out(const u16* __restrict__ wo_hi,
                                             const u16* __restrict__ wo_lo,
                                             const u16* __restrict__ ih,
                                             const u16* __restrict__ il,
                                             float* __restrict__ out) {
    const int j0 = blockIdx.x * 64;
    const int c0 = blockIdx.y * 64;
    const int b  = blockIdx.z;
    const int t  = threadIdx.x;
    const int w = t >> 6, lane = t & 63, mcol = lane & 15, quad = lane >> 4;

    const u16* ah = wo_hi + (size_t)(c0 + w * 16 + mcol) * 512 + quad * 8;
    const u16* al = wo_lo + (size_t)(c0 + w * 16 + mcol) * 512 + quad * 8;
    const u16* xh = ih + ((size_t)b * NPOS + j0 + mcol) * 512 + quad * 8;
    const u16* xl = il + ((size_t)b * NPOS + j0 + mcol) * 512 + quad * 8;

    f32x4 c[4];
#pragma unroll
    for (int nf = 0; nf < 4; ++nf) c[nf] = (f32x4){0.f, 0.f, 0.f, 0.f};
#pragma unroll
    for (int kc = 0; kc < 16; ++kc) {
        const bf16x8 A  = *(const bf16x8*)&ah[kc * 32];
        const bf16x8 Al = *(const bf16x8*)&al[kc * 32];
        bf16x8 Bh[4], Bl[4];
#pragma unroll
        for (int nf = 0; nf < 4; ++nf) {
            Bh[nf] = *(const bf16x8*)&xh[(size_t)nf * 16 * 512 + kc * 32];
            Bl[nf] = *(const bf16x8*)&xl[(size_t)nf * 16 * 512 + kc * 32];
        }
#pragma unroll
        for (int nf = 0; nf < 4; ++nf) {
            c[nf] = __builtin_amdgcn_mfma_f32_16x16x32_bf16(A,  Bh[nf], c[nf], 0, 0, 0);
            c[nf] = __builtin_amdgcn_mfma_f32_16x16x32_bf16(A,  Bl[nf], c[nf], 0, 0, 0);
            c[nf] = __builtin_amdgcn_mfma_f32_16x16x32_bf16(Al, Bh[nf], c[nf], 0, 0, 0);
        }
    }
    float* ob = out + ((size_t)b * CC + c0 + w * 16) * NPOS + j0;
#pragma unroll
    for (int nf = 0; nf < 4; ++nf)
#pragma unroll
        for (int r = 0; r < 4; ++r)
            ob[(size_t)(quad * 4 + r) * NPOS + nf * 16 + mcol] = c[nf][r];
}

extern "C" void kernel_launch(void* const* d_in, const int* in_sizes, int n_in,
                              void* d_out, int out_size, void* d_ws, size_t ws_size,
                              hipStream_t stream) {
    const float* fmap    = (const float*)d_in[0];
    const float* gamma   = (const float*)d_in[1];
    const float* w_qk    = (const float*)d_in[2];
    const float* w_v     = (const float*)d_in[3];
    const float* null_kv = (const float*)d_in[4];
    const float* w_out   = (const float*)d_in[5];
    float* out = (float*)d_out;

    u16* ws16 = (u16*)d_ws;
    u16* xbuf   = ws16;                     // 2*2304*256   = 1,179,648
    u16* wbuf   = xbuf + 1179648;           // 1024*256     =   262,144
    u16* wo_hi  = wbuf + 262144;            // 256*512      =   131,072
    u16* wo_lo  = wo_hi + 131072;           //                  131,072
    u16* qkh    = wo_lo + 131072;           // 16*2304*64   = 2,359,296
    u16* vtb    = qkh + 2359296;            // 16*72*64*32  = 2,359,296
    u16* in_hi  = vtb + 2359296;            // 2*2304*512   = 2,359,296
    u16* in_lo  = in_hi + 2359296;          //                2,359,296
    float* sqbuf = (float*)(in_lo + 2359296);   // 2*8*2304 fp32
    float* ndbuf = sqbuf + 36864;
    float* nk2b  = ndbuf + 36864;           // 8 fp32
    // total ~ 27 MB

    hipLaunchKernelGGL(k_prep, dim3(NT, 2),     dim3(256), 0, stream, fmap, gamma, xbuf);
    hipLaunchKernelGGL(k_wcvt, dim3(384),       dim3(256), 0, stream, w_qk, w_v, w_out, null_kv, wbuf, wo_hi, wo_lo, nk2b);
    hipLaunchKernelGGL(k_proj, dim3(NT, 16, 2), dim3(256), 0, stream, xbuf, wbuf, null_kv, qkh, vtb, sqbuf, ndbuf);
    hipLaunchKernelGGL(k_attn, dim3(144, 16),   dim3(256), 0, stream, qkh, vtb, null_kv, nk2b, sqbuf, ndbuf, in_hi, in_lo);
    hipLaunchKernelGGL(k_out,  dim3(NT, 4, 2),  dim3(256), 0, stream, wo_hi, wo_lo, in_hi, in_lo, out);
}